// Round 4
// baseline (561.686 us; speedup 1.0000x reference)
//
#include <hip/hip_runtime.h>

#define RN      128   // REAL
#define START_T 126
#define END_T   127

// DPP cross-lane helper (all-lane-active contexts only)
#define FDPP(x, ctrl) __int_as_float(__builtin_amdgcn_update_dpp(0, __float_as_int(x), (ctrl), 0xF, 0xF, true))

// padded p layout: 8 chunks of 16 words at stride 20 -> the 8 b128 addresses of a wave
// partition all 32 banks (conflict-free broadcast)
__device__ __forceinline__ int pword(int r) { return ((r >> 4) * 20) + (r & 15); }
// padded emit layout: stride 40 -> writer reads rg+32s hit 32 distinct banks
__device__ __forceinline__ int eword(int r) { return ((r >> 5) * 40) + (r & 31); }

__global__ __launch_bounds__(256, 1)
void crf_nll_kernel(const float* __restrict__ X,
                    const int*   __restrict__ y,
                    const float* __restrict__ trans,
                    float* __restrict__ out, int L)
{
    const int b   = blockIdx.x;
    const int tid = threadIdx.x;
    const int s   = tid & 7;    // j-chunk 0..7 (16 wide)
    const int rg  = tid >> 3;   // row group 0..31 -> rows rg+32k, k=0..3
    const int wv  = tid >> 6;   // wave 0..3

    __shared__ __align__(16) float pb[2][160];    // double-buffered scaled probs (stride-20 pad)
    __shared__ __align__(16) float earr[2][160];  // double-buffered exp(emit) (stride-40 pad)
    __shared__ float tmp4[4];
    __shared__ float tmp2[2];

    const float* Xb = X + (size_t)b * (size_t)L * RN;
    const int*   yb = y + (size_t)b * L;

    // ---------------- gold path score ----------------
    float g = 0.f;
    for (int t = tid; t < L; t += 256) {
        int yt = yb[t];
        int yp = t ? yb[t - 1] : START_T;
        g += trans[yt * RN + yp] + Xb[(size_t)t * RN + yt];
    }
    #pragma unroll
    for (int off = 1; off < 64; off <<= 1) g += __shfl_xor(g, off, 64);
    if ((tid & 63) == 0) tmp4[wv] = g;

    // zero p buffers, seed onehot(START) in buffer 0
    for (int w = tid; w < 320; w += 256)
        ((float*)pb)[w] = (w == pword(START_T)) ? 1.f : 0.f;

    // E = exp(trans) in VGPRs: 4 rows (rg+32k) x 16 cols (chunk s).
    // Masked entries (-1e4) underflow to exactly 0 -> semiring mask preserved.
    float E[4][16];
    #pragma unroll
    for (int k = 0; k < 4; ++k) {
        const float* tr = trans + (rg + 32 * k) * RN + s * 16;
        #pragma unroll
        for (int j = 0; j < 16; ++j) E[k][j] = __expf(tr[j]);
    }

    // emit team: waves 0,1 (tid<128) produce exp(X[t+1]) into earr during step t
    const bool team = (tid < RN);
    const int  ew   = eword(tid & 127);
    float xraw = 0.f;
    if (team) {
        earr[0][ew] = __expf(Xb[tid]);
        xraw = (L > 1) ? Xb[RN + tid] : Xb[tid];
    }

    const int erow = rg + 32 * (s & 3);   // row whose emit this lane applies (s<4 write)
    const int esl  = eword(erow);         // loop-invariant emit slot
    const int wout = pword(erow);         // loop-invariant p write slot

    float goldv = 0.f;
    __syncthreads();
    if (tid == 0)
        goldv = tmp4[0] + tmp4[1] + tmp4[2] + tmp4[3] + trans[END_T * RN + yb[L - 1]];

    float logscale = 0.f;

    auto step = [&](int t, const float* __restrict__ ps, float* __restrict__ pd,
                    const float* __restrict__ esrc, float* __restrict__ edst) {
        // emit pipeline (team waves; wave-uniform branch); overlaps the ds_read latency
        if (team) {
            edst[ew] = __expf(xraw);
            int tt = t + 2; if (tt > L - 1) tt = L - 1;
            xraw = Xb[(size_t)tt * RN + tid];
        }
        float ee = esrc[esl];   // exp(X[t][erow]); conflict-free (stride-40 pad)

        // my 16-wide chunk of p_t (4x ds_read_b128, conflict-free broadcast)
        const float4* P4 = (const float4*)(ps + 20 * s);
        float4 q0 = P4[0], q1 = P4[1], q2 = P4[2], q3 = P4[3];
        float pq[16] = { q0.x,q0.y,q0.z,q0.w, q1.x,q1.y,q1.z,q1.w,
                         q2.x,q2.y,q2.z,q2.w, q3.x,q3.y,q3.z,q3.w };

        // 4 rows x 16 cols, 2 accumulators per row (8 independent depth-8 chains)
        float v[4];
        #pragma unroll
        for (int k = 0; k < 4; ++k) {
            float a0 = 0.f, a1 = 0.f;
            #pragma unroll
            for (int j = 0; j < 16; j += 2) {
                a0 = fmaf(E[k][j],     pq[j],     a0);
                a1 = fmaf(E[k][j + 1], pq[j + 1], a1);
            }
            v[k] = a0 + a1;
        }

        // every 4th step: global max of p_t, redundantly per 8-lane group
        // (each group's chunks cover all 128 entries -> identical result everywhere)
        float invv = 1.0f;
        if ((t & 3) == 2) {
            float m0 = fmaxf(fmaxf(pq[0],  pq[1]),  fmaxf(pq[2],  pq[3]));
            float m1 = fmaxf(fmaxf(pq[4],  pq[5]),  fmaxf(pq[6],  pq[7]));
            float m2 = fmaxf(fmaxf(pq[8],  pq[9]),  fmaxf(pq[10], pq[11]));
            float m3 = fmaxf(fmaxf(pq[12], pq[13]), fmaxf(pq[14], pq[15]));
            float m = fmaxf(fmaxf(m0, m1), fmaxf(m2, m3));
            m = fmaxf(m, FDPP(m, 0xB1));    // xor1
            m = fmaxf(m, FDPP(m, 0x4E));    // xor2
            m = fmaxf(m, FDPP(m, 0x141));   // cross-quad within 8
            invv = 1.0f / m;
            logscale += __logf(m);
        }

        // 8-way cross-chunk combine per row: 3 DPP-add stages, no LDS
        #pragma unroll
        for (int k = 0; k < 4; ++k) {
            v[k] += FDPP(v[k], 0xB1);
            v[k] += FDPP(v[k], 0x4E);
            v[k] += FDPP(v[k], 0x141);
        }

        // writer lanes s<4 publish row rg+32s; ONE barrier per step
        float vout = (s & 2) ? ((s & 1) ? v[3] : v[2]) : ((s & 1) ? v[1] : v[0]);
        if (s < 4) pd[wout] = vout * (ee * invv);
        __syncthreads();
    };

    int t = 0;
    for (; t + 1 < L; t += 2) {
        step(t,     pb[0], pb[1], earr[0], earr[1]);
        step(t + 1, pb[1], pb[0], earr[1], earr[0]);
    }
    const float* pf = pb[0];
    if (t < L) { step(t, pb[0], pb[1], earr[0], earr[1]); pf = pb[1]; }

    // ---------------- logZ = logscale + log(sum p_L * exp(trans[END,:])) ----------------
    float z = 0.f;
    if (tid < RN) {
        z = pf[pword(tid)] * __expf(trans[END_T * RN + tid]);
        #pragma unroll
        for (int off = 1; off < 64; off <<= 1) z += __shfl_xor(z, off, 64);
        if ((tid & 63) == 0) tmp2[tid >> 6] = z;
    }
    __syncthreads();
    if (tid == 0) out[b] = logscale + __logf(tmp2[0] + tmp2[1]) - goldv;
}

extern "C" void kernel_launch(void* const* d_in, const int* in_sizes, int n_in,
                              void* d_out, int out_size, void* d_ws, size_t ws_size,
                              hipStream_t stream) {
    const float* X     = (const float*)d_in[0];
    const int*   y     = (const int*)d_in[1];
    const float* trans = (const float*)d_in[2];
    float*       out   = (float*)d_out;

    const int B = out_size;            // 256
    const int L = in_sizes[1] / B;     // 1024

    crf_nll_kernel<<<dim3(B), dim3(256), 0, stream>>>(X, y, trans, out, L);
}

// Round 5
// 552.236 us; speedup vs baseline: 1.0171x; 1.0171x over previous
//
#include <hip/hip_runtime.h>

#define RN      128   // REAL
#define START_T 126
#define END_T   127

typedef short v8s __attribute__((ext_vector_type(8)));   // 8 x bf16 (4 VGPRs) MFMA A/B frag
typedef float v4f __attribute__((ext_vector_type(4)));   // 4 x f32 MFMA C/D frag

#define IDPP(x, ctrl) __builtin_amdgcn_update_dpp(0, (x), (ctrl), 0xF, 0xF, true)

// bf16 round-to-nearest-even pack / unpack
__device__ __forceinline__ unsigned short f2bf(float f) {
    unsigned u = __float_as_uint(f);
    u += 0x7fffu + ((u >> 16) & 1u);
    return (unsigned short)(u >> 16);
}
__device__ __forceinline__ float bf2f(unsigned short s) {
    return __uint_as_float(((unsigned)s) << 16);
}

__global__ __launch_bounds__(256, 1)
void crf_nll_kernel(const float* __restrict__ X,
                    const int*   __restrict__ y,
                    const float* __restrict__ trans,
                    float* __restrict__ out, int L)
{
    const int b    = blockIdx.x;
    const int tid  = threadIdx.x;
    const int lane = tid & 63;
    const int w    = tid >> 6;      // wave 0..3 -> rows 32w..32w+31 (tiles 2w, 2w+1)
    const int col  = lane & 15;     // MFMA m/n lane index
    const int quad = lane >> 4;     // MFMA k-group / row-group

    __shared__ __align__(16) unsigned short pbf[2][RN];  // scaled probs, bf16, double-buffered
    __shared__ __align__(16) float earr[2][RN];          // exp(emit), fp32, double-buffered
    __shared__ float tmp4[4];

    const float* Xb = X + (size_t)b * (size_t)L * RN;
    const int*   yb = y + (size_t)b * L;

    // ---------------- gold path score ----------------
    float g = 0.f;
    for (int t = tid; t < L; t += 256) {
        int yt = yb[t];
        int yp = t ? yb[t - 1] : START_T;
        g += trans[yt * RN + yp] + Xb[(size_t)t * RN + yt];
    }
    #pragma unroll
    for (int off = 1; off < 64; off <<= 1) g += __shfl_xor(g, off, 64);
    if ((tid & 63) == 0) tmp4[w] = g;

    // zero p buffers; seed bf16(1.0) at START in buffer 0
    for (int i2 = tid; i2 < 2 * RN; i2 += 256)
        ((unsigned short*)pbf)[i2] = (i2 == START_T) ? (unsigned short)0x3F80 : (unsigned short)0;

    // ---- A-fragments: E = exp(trans) in bf16, resident in registers all kernel ----
    // A[m = col + 16*T + 32*w][k = 32*c + 8*quad + j]  (verified 16x16x32 A layout)
    // Masked entries (-1e4) -> exp underflow -> exactly 0: semiring mask preserved.
    v8s Ef[2][4];
    #pragma unroll
    for (int T = 0; T < 2; ++T) {
        #pragma unroll
        for (int c = 0; c < 4; ++c) {
            const float* tr = trans + (32 * w + 16 * T + col) * RN + 32 * c + 8 * quad;
            v8s v;
            #pragma unroll
            for (int j = 0; j < 8; ++j) v[j] = (short)f2bf(__expf(tr[j]));
            Ef[T][c] = v;
        }
    }

    // emit team: threads 0..127 produce exp(X[t+1]) during step t
    const bool team = (tid < RN);
    float xraw = 0.f;
    if (team) {
        earr[0][tid] = __expf(Xb[tid]);
        xraw = (L > 1) ? Xb[RN + tid] : Xb[tid];
    }

    float goldv = 0.f;
    __syncthreads();
    if (tid == 0)
        goldv = tmp4[0] + tmp4[1] + tmp4[2] + tmp4[3] + trans[END_T * RN + yb[L - 1]];

    float logscale = 0.f;
    float mxf = 1.0f;

    auto step = [&](int t, const unsigned short* __restrict__ ps, unsigned short* __restrict__ pd,
                    const float* __restrict__ es, float* __restrict__ ed) {
        // emit pipeline (off critical chain)
        if (team) {
            ed[tid] = __expf(xraw);
            int tt = t + 2; if (tt > L - 1) tt = L - 1;
            xraw = Xb[(size_t)tt * RN + tid];
        }

        // B-fragments: p replicated over all 16 columns -> frag value depends only on k.
        // chunk c frag = 16B at byte offset c*64 + quad*16  -> v8s index c*4 + quad
        const v8s* PB = (const v8s*)ps;
        v8s B0 = PB[0 * 4 + quad];
        v8s B1 = PB[1 * 4 + quad];
        v8s B2 = PB[2 * 4 + quad];
        v8s B3 = PB[3 * 4 + quad];

        // every 4th step: global max of p_t (bf16 bits; p>=0 so uint order == float order)
        if ((t & 3) == 1) {
            v8s pm = PB[col];   // 16 lanes x 16B cover all 256B (4x replicated per wave)
            int mi = (unsigned short)pm[0];
            #pragma unroll
            for (int j = 1; j < 8; ++j) { int u = (unsigned short)pm[j]; mi = (u > mi) ? u : mi; }
            int d;
            d = IDPP(mi, 0xB1);  mi = (d > mi) ? d : mi;   // xor1
            d = IDPP(mi, 0x4E);  mi = (d > mi) ? d : mi;   // xor2
            d = IDPP(mi, 0x141); mi = (d > mi) ? d : mi;   // 8-group
            d = IDPP(mi, 0x140); mi = (d > mi) ? d : mi;   // 16-group -> global (cols cover all)
            mxf = __uint_as_float(((unsigned)mi) << 16);
        }
        float invv = 1.0f;
        if ((t & 3) == 2) {      // stale-by-one apply (bounded drift; exact bookkeeping)
            invv = 1.0f / mxf;
            logscale += __logf(mxf);
        }

        // 8 MFMAs on the matrix pipe: two independent chains of 4 (tiles 2w, 2w+1)
        v4f a0 = {0.f, 0.f, 0.f, 0.f};
        v4f a1 = {0.f, 0.f, 0.f, 0.f};
        a0 = __builtin_amdgcn_mfma_f32_16x16x32_bf16(Ef[0][0], B0, a0, 0, 0, 0);
        a1 = __builtin_amdgcn_mfma_f32_16x16x32_bf16(Ef[1][0], B0, a1, 0, 0, 0);
        a0 = __builtin_amdgcn_mfma_f32_16x16x32_bf16(Ef[0][1], B1, a0, 0, 0, 0);
        a1 = __builtin_amdgcn_mfma_f32_16x16x32_bf16(Ef[1][1], B1, a1, 0, 0, 0);
        a0 = __builtin_amdgcn_mfma_f32_16x16x32_bf16(Ef[0][2], B2, a0, 0, 0, 0);
        a1 = __builtin_amdgcn_mfma_f32_16x16x32_bf16(Ef[1][2], B2, a1, 0, 0, 0);
        a0 = __builtin_amdgcn_mfma_f32_16x16x32_bf16(Ef[0][3], B3, a0, 0, 0, 0);
        a1 = __builtin_amdgcn_mfma_f32_16x16x32_bf16(Ef[1][3], B3, a1, 0, 0, 0);

        // epilogue: col-0 lanes hold rows 4*quad..4*quad+3 of each tile (all cols identical)
        if (col == 0) {
            int r0 = 32 * w + 4 * quad;
            float4 e0 = *(const float4*)&es[r0];
            float4 e1 = *(const float4*)&es[r0 + 16];
            ushort4 o0, o1;
            o0.x = f2bf(a0[0] * e0.x * invv);
            o0.y = f2bf(a0[1] * e0.y * invv);
            o0.z = f2bf(a0[2] * e0.z * invv);
            o0.w = f2bf(a0[3] * e0.w * invv);
            o1.x = f2bf(a1[0] * e1.x * invv);
            o1.y = f2bf(a1[1] * e1.y * invv);
            o1.z = f2bf(a1[2] * e1.z * invv);
            o1.w = f2bf(a1[3] * e1.w * invv);
            *(ushort4*)(pd + r0)      = o0;   // 8B aligned ds_write_b64
            *(ushort4*)(pd + r0 + 16) = o1;
        }
        __syncthreads();   // ONE barrier per step
    };

    int t = 0;
    for (; t + 1 < L; t += 2) {
        step(t,     pbf[0], pbf[1], earr[0], earr[1]);
        step(t + 1, pbf[1], pbf[0], earr[1], earr[0]);
    }
    const unsigned short* pf = pbf[0];
    if (t < L) { step(t, pbf[0], pbf[1], earr[0], earr[1]); pf = pbf[1]; }

    // ---------------- logZ = logscale + log(sum p_L * exp(trans[END,:])) ----------------
    float z = 0.f;
    if (tid < RN) {
        z = bf2f(pf[tid]) * __expf(trans[END_T * RN + tid]);
        #pragma unroll
        for (int off = 1; off < 64; off <<= 1) z += __shfl_xor(z, off, 64);
        if ((tid & 63) == 0) tmp4[tid >> 6] = z;
    }
    __syncthreads();
    if (tid == 0) out[b] = logscale + __logf(tmp4[0] + tmp4[1]) - goldv;
}

extern "C" void kernel_launch(void* const* d_in, const int* in_sizes, int n_in,
                              void* d_out, int out_size, void* d_ws, size_t ws_size,
                              hipStream_t stream) {
    const float* X     = (const float*)d_in[0];
    const int*   y     = (const int*)d_in[1];
    const float* trans = (const float*)d_in[2];
    float*       out   = (float*)d_out;

    const int B = out_size;            // 256
    const int L = in_sizes[1] / B;     // 1024

    crf_nll_kernel<<<dim3(B), dim3(256), 0, stream>>>(X, y, trans, out, L);
}

// Round 6
// 529.315 us; speedup vs baseline: 1.0612x; 1.0433x over previous
//
#include <hip/hip_runtime.h>

#define RN      128   // REAL
#define START_T 126
#define END_T   127
#define GS      32    // X staging group size (steps per stage)

typedef short v8s __attribute__((ext_vector_type(8)));   // 8 x bf16 (4 VGPRs) MFMA A/B frag
typedef float v4f __attribute__((ext_vector_type(4)));   // 4 x f32 MFMA C/D frag

#define IDPP(x, ctrl) __builtin_amdgcn_update_dpp(0, (x), (ctrl), 0xF, 0xF, true)

// bf16 round-to-nearest-even pack / unpack
__device__ __forceinline__ unsigned short f2bf(float f) {
    unsigned u = __float_as_uint(f);
    u += 0x7fffu + ((u >> 16) & 1u);
    return (unsigned short)(u >> 16);
}
__device__ __forceinline__ float bf2f(unsigned short s) {
    return __uint_as_float(((unsigned)s) << 16);
}

__global__ __launch_bounds__(256, 1)
void crf_nll_kernel(const float* __restrict__ X,
                    const int*   __restrict__ y,
                    const float* __restrict__ trans,
                    float* __restrict__ out, int L)
{
    const int b    = blockIdx.x;
    const int tid  = threadIdx.x;
    const int lane = tid & 63;
    const int w    = tid >> 6;      // wave 0..3 -> rows 32w..32w+31 (tiles 2w, 2w+1)
    const int col  = lane & 15;     // MFMA m/n lane index
    const int quad = lane >> 4;     // MFMA k-group / row-group

    __shared__ __align__(16) unsigned short pbf[2][RN];   // scaled probs, bf16, double-buffered
    __shared__ __align__(16) float xst[2][GS][RN];        // exp(X) staged GS steps at a time
    __shared__ float tmp4[4];

    const float* Xb = X + (size_t)b * (size_t)L * RN;
    const int*   yb = y + (size_t)b * L;

    // ---------------- gold path score ----------------
    float g = 0.f;
    for (int t = tid; t < L; t += 256) {
        int yt = yb[t];
        int yp = t ? yb[t - 1] : START_T;
        g += trans[yt * RN + yp] + Xb[(size_t)t * RN + yt];
    }
    #pragma unroll
    for (int off = 1; off < 64; off <<= 1) g += __shfl_xor(g, off, 64);
    if ((tid & 63) == 0) tmp4[w] = g;

    // zero p buffers; seed bf16(1.0) at START in buffer 0
    for (int i2 = tid; i2 < 2 * RN; i2 += 256)
        ((unsigned short*)pbf)[i2] = (i2 == START_T) ? (unsigned short)0x3F80 : (unsigned short)0;

    // ---- A-fragments: E = exp(trans) in bf16, resident in registers all kernel ----
    // A[m = col + 16*T + 32*w][k = 32*c + 8*quad + j]
    // Masked entries (-1e4) -> exp underflow -> exactly 0: semiring mask preserved.
    v8s Ef[2][4];
    #pragma unroll
    for (int T = 0; T < 2; ++T) {
        #pragma unroll
        for (int c = 0; c < 4; ++c) {
            const float* tr = trans + (32 * w + 16 * T + col) * RN + 32 * c + 8 * quad;
            v8s v;
            #pragma unroll
            for (int j = 0; j < 8; ++j) v[j] = (short)f2bf(__expf(tr[j]));
            Ef[T][c] = v;
        }
    }

    // ---- X staging: exp(X[t0..t0+GS)) -> xst[buf]; GS*RN floats, contiguous in X ----
    const size_t lim = (size_t)L * RN;
    auto stage = [&](int t0, int buf) {
        const size_t base = (size_t)t0 * RN;
        float* dst = &xst[buf][0][0];
        #pragma unroll
        for (int c = 0; c < (GS * RN) / (256 * 4); ++c) {
            const int f = 4 * tid + c * 1024;
            float4 v;
            if (base + f + 3 < lim) {
                v = *(const float4*)(Xb + base + f);
            } else {                     // clamped tail (values unused for t >= L)
                float* pv = (float*)&v;
                #pragma unroll
                for (int j = 0; j < 4; ++j) {
                    size_t ix = base + f + j; if (ix >= lim) ix = lim - 1;
                    pv[j] = Xb[ix];
                }
            }
            float4 e;
            e.x = __expf(v.x); e.y = __expf(v.y); e.z = __expf(v.z); e.w = __expf(v.w);
            *(float4*)(dst + f) = e;
        }
    };
    stage(0, 0);   // pre-stage group 0

    float goldv = 0.f;
    __syncthreads();
    if (tid == 0)
        goldv = tmp4[0] + tmp4[1] + tmp4[2] + tmp4[3] + trans[END_T * RN + yb[L - 1]];

    float logscale = 0.f;
    float mxf = 1.0f;
    const int r0 = 32 * w + 4 * quad;   // epilogue row base (col==0 lanes)

    auto step = [&](int t, const float* __restrict__ es,
                    const unsigned short* __restrict__ ps, unsigned short* __restrict__ pd,
                    bool do_stage, int tstage, int bufn) {
        if (do_stage) stage(tstage, bufn);   // global loads issue right after prev barrier

        // emit prefetch (col==0 lanes), overlaps the B-frag ds_read latency
        float4 e0, e1;
        if (col == 0) {
            e0 = *(const float4*)&es[r0];
            e1 = *(const float4*)&es[r0 + 16];
        }

        // B-fragments: p replicated over all 16 columns -> frag value depends only on k.
        const v8s* PB = (const v8s*)ps;
        v8s B0 = PB[0 * 4 + quad];
        v8s B1 = PB[1 * 4 + quad];
        v8s B2 = PB[2 * 4 + quad];
        v8s B3 = PB[3 * 4 + quad];

        // every 4th step: global max of p_t (bf16 bits; p>=0 so int order == float order)
        if ((t & 3) == 1) {
            v8s pm = PB[col];   // 16 lanes x 16B cover all 256B
            int mi = (unsigned short)pm[0];
            #pragma unroll
            for (int j = 1; j < 8; ++j) { int u = (unsigned short)pm[j]; mi = (u > mi) ? u : mi; }
            int d;
            d = IDPP(mi, 0xB1);  mi = (d > mi) ? d : mi;   // xor1
            d = IDPP(mi, 0x4E);  mi = (d > mi) ? d : mi;   // xor2
            d = IDPP(mi, 0x141); mi = (d > mi) ? d : mi;   // 8-group
            d = IDPP(mi, 0x140); mi = (d > mi) ? d : mi;   // 16-group -> global
            mxf = __uint_as_float(((unsigned)mi) << 16);
        }
        float invv = 1.0f;
        if ((t & 3) == 2) {      // stale-by-one apply (bounded drift; exact bookkeeping)
            invv = 1.0f / mxf;
            logscale += __logf(mxf);
        }

        // 8 MFMAs: two independent chains of 4 (tiles 2w, 2w+1)
        v4f a0 = {0.f, 0.f, 0.f, 0.f};
        v4f a1 = {0.f, 0.f, 0.f, 0.f};
        a0 = __builtin_amdgcn_mfma_f32_16x16x32_bf16(Ef[0][0], B0, a0, 0, 0, 0);
        a1 = __builtin_amdgcn_mfma_f32_16x16x32_bf16(Ef[1][0], B0, a1, 0, 0, 0);
        a0 = __builtin_amdgcn_mfma_f32_16x16x32_bf16(Ef[0][1], B1, a0, 0, 0, 0);
        a1 = __builtin_amdgcn_mfma_f32_16x16x32_bf16(Ef[1][1], B1, a1, 0, 0, 0);
        a0 = __builtin_amdgcn_mfma_f32_16x16x32_bf16(Ef[0][2], B2, a0, 0, 0, 0);
        a1 = __builtin_amdgcn_mfma_f32_16x16x32_bf16(Ef[1][2], B2, a1, 0, 0, 0);
        a0 = __builtin_amdgcn_mfma_f32_16x16x32_bf16(Ef[0][3], B3, a0, 0, 0, 0);
        a1 = __builtin_amdgcn_mfma_f32_16x16x32_bf16(Ef[1][3], B3, a1, 0, 0, 0);

        // epilogue: col-0 lanes hold rows r0..r0+3 (tile 2w) and r0+16.. (tile 2w+1)
        if (col == 0) {
            ushort4 o0, o1;
            o0.x = f2bf(a0[0] * e0.x * invv);
            o0.y = f2bf(a0[1] * e0.y * invv);
            o0.z = f2bf(a0[2] * e0.z * invv);
            o0.w = f2bf(a0[3] * e0.w * invv);
            o1.x = f2bf(a1[0] * e1.x * invv);
            o1.y = f2bf(a1[1] * e1.y * invv);
            o1.z = f2bf(a1[2] * e1.z * invv);
            o1.w = f2bf(a1[3] * e1.w * invv);
            *(ushort4*)(pd + r0)      = o0;   // 8B aligned ds_write_b64
            *(ushort4*)(pd + r0 + 16) = o1;
        }
        __syncthreads();   // ONE barrier per step; drains vmcnt only on staging steps
    };

    const int G = L / GS;          // full groups (L=1024 -> 32)
    for (int gi = 0; gi < G; ++gi) {
        const int t0  = gi * GS;
        const int buf = gi & 1;
        const bool stg = (t0 + GS) < L;
        #pragma unroll
        for (int s = 0; s < GS; ++s) {
            const int t = t0 + s;
            step(t, &xst[buf][s][0],
                 pbf[t & 1], pbf[(t + 1) & 1],
                 (s == 0) && stg, t0 + GS, buf ^ 1);
        }
    }
    // tail (L % GS != 0): group G was staged by group G-1 (clamped)
    for (int t = G * GS; t < L; ++t) {
        step(t, &xst[G & 1][t - G * GS][0],
             pbf[t & 1], pbf[(t + 1) & 1], false, 0, 0);
    }
    const unsigned short* pf = pbf[L & 1];

    // ---------------- logZ = logscale + log(sum p_L * exp(trans[END,:])) ----------------
    float z = 0.f;
    if (tid < RN) {
        z = bf2f(pf[tid]) * __expf(trans[END_T * RN + tid]);
        #pragma unroll
        for (int off = 1; off < 64; off <<= 1) z += __shfl_xor(z, off, 64);
        if ((tid & 63) == 0) tmp4[tid >> 6] = z;
    }
    __syncthreads();
    if (tid == 0) out[b] = logscale + __logf(tmp4[0] + tmp4[1]) - goldv;
}

extern "C" void kernel_launch(void* const* d_in, const int* in_sizes, int n_in,
                              void* d_out, int out_size, void* d_ws, size_t ws_size,
                              hipStream_t stream) {
    const float* X     = (const float*)d_in[0];
    const int*   y     = (const int*)d_in[1];
    const float* trans = (const float*)d_in[2];
    float*       out   = (float*)d_out;

    const int B = out_size;            // 256
    const int L = in_sizes[1] / B;     // 1024

    crf_nll_kernel<<<dim3(B), dim3(256), 0, stream>>>(X, y, trans, out, L);
}